// Round 2
// 456.790 us; speedup vs baseline: 1.0062x; 1.0062x over previous
//
#include <hip/hip_runtime.h>

// x[B=16, C=64, H=256, W=256] fp32 — single pass over x.
// Softmax-over-h with constant shift K=8 (exact in the ratio; n ~ chi(64) ≈ 8,
// so exp(n-8) is in safe range — validated at absmax ~4.9e-4):
//   e[b,h,w]     = exp(sqrt(sum_c x^2) - 8)
//   den[b,w]     = sum_h e
//   comp[b,c,w]  = sum_h x*e / (den*(1+1e-8))
//   out[b,c,h,w] = comp broadcast over h
// k_pass1 computes per-h-chunk partials of (sum_h x*e) and (sum_h e) reading x
// exactly once; k_pass2 combines chunks, divides, broadcast-writes out.
//
// R1 change vs 460µs baseline: pass1 was ~170 VGPR (xv[16]+acc[16]) -> 2 waves/SIMD,
// latency-bound. Now 512-thread blocks, 8 channel-groups x 8 channels/thread
// (xv[8]+acc[8] ~ 90 VGPR, __launch_bounds__(512,4)) -> 16 waves/CU at same traffic.
// pass2: removed 2nd barrier + fin buffer (redundant per-thread final reduce).
// R2: identical resubmit — R1 bench was an infra failure (container acquisition),
// not a kernel verdict.

constexpr int B = 16, C = 64, H = 256, W = 256, W4 = 64;
constexpr int HC = 32;          // h-chunks per image
constexpr int HPC = H / HC;     // 8 h per chunk
constexpr float KSUB = 8.0f;

typedef float nfloat4 __attribute__((ext_vector_type(4)));

__device__ __forceinline__ float4 f4add(float4 a, float4 b) {
    return make_float4(a.x + b.x, a.y + b.y, a.z + b.z, a.w + b.w);
}

// ---------------- Pass 1: norms + exp + partial sums, one x read ----------------
// 512 blocks x 512 thr; block = (b, hc); thread = (cg in [0,8), w4 in [0,64)).
__global__ __launch_bounds__(512, 4) void k_pass1(const float* __restrict__ x,
                                                  float4* __restrict__ pcomp,  // [B][HC][C][W4]
                                                  float4* __restrict__ pden) { // [B][HC][W4]
    __shared__ float4 red[2][8][64];   // double-buffered: 1 sync per h
    int blk = blockIdx.x;
    int b = blk >> 5, hc = blk & 31;
    int t = threadIdx.x, cg = t >> 6, w4 = t & 63;
    int h0 = hc * HPC;

    const float4* xb = (const float4*)x + ((size_t)(b * C + cg * 8) * H + h0) * W4 + w4;

    float4 acc[8];
#pragma unroll
    for (int j = 0; j < 8; ++j) acc[j] = make_float4(0.f, 0.f, 0.f, 0.f);
    float4 dacc = make_float4(0.f, 0.f, 0.f, 0.f);

    for (int hh = 0; hh < HPC; ++hh) {
        float4 xv[8];
        float4 ps = make_float4(0.f, 0.f, 0.f, 0.f);
#pragma unroll
        for (int j = 0; j < 8; ++j) {
            xv[j] = xb[(size_t)j * H * W4 + (size_t)hh * W4];   // coalesced 16B/lane
            ps.x += xv[j].x * xv[j].x; ps.y += xv[j].y * xv[j].y;
            ps.z += xv[j].z * xv[j].z; ps.w += xv[j].w * xv[j].w;
        }
        red[hh & 1][cg][w4] = ps;
        __syncthreads();
        float4 s = make_float4(0.f, 0.f, 0.f, 0.f);
#pragma unroll
        for (int g = 0; g < 8; ++g) s = f4add(s, red[hh & 1][g][w4]);
        float4 e = make_float4(__expf(sqrtf(s.x) - KSUB), __expf(sqrtf(s.y) - KSUB),
                               __expf(sqrtf(s.z) - KSUB), __expf(sqrtf(s.w) - KSUB));
        if (cg == 0) dacc = f4add(dacc, e);
#pragma unroll
        for (int j = 0; j < 8; ++j) {
            acc[j].x += xv[j].x * e.x; acc[j].y += xv[j].y * e.y;
            acc[j].z += xv[j].z * e.z; acc[j].w += xv[j].w * e.w;
        }
    }

    size_t pc = ((size_t)(b * HC + hc) * C + cg * 8) * W4 + w4;
#pragma unroll
    for (int j = 0; j < 8; ++j)
        pcomp[pc + (size_t)j * W4] = acc[j];
    if (cg == 0)
        pden[(size_t)(b * HC + hc) * W4 + w4] = dacc;
}

// ---------------- Pass 2: combine chunks, divide, broadcast write ----------------
// 1024 blocks x 256 thr; block = (b, c); thread = (hq in [0,4), w4).
__global__ __launch_bounds__(256) void k_pass2(const float4* __restrict__ pcomp,
                                               const float4* __restrict__ pden,
                                               float* __restrict__ out) {
    __shared__ float4 redc[4][64], redd[4][64];
    int blk = blockIdx.x;
    int b = blk >> 6, c = blk & 63;
    int t = threadIdx.x, hq = t >> 6, w4 = t & 63;

    float4 sc = make_float4(0.f, 0.f, 0.f, 0.f), sd = sc;
#pragma unroll
    for (int k = 0; k < 8; ++k) {
        int hc = hq * 8 + k;
        sc = f4add(sc, pcomp[((size_t)(b * HC + hc) * C + c) * W4 + w4]);
        sd = f4add(sd, pden[(size_t)(b * HC + hc) * W4 + w4]);   // L2/L3-hot, shared by 64 c
    }
    redc[hq][w4] = sc;
    redd[hq][w4] = sd;
    __syncthreads();
    // every thread does the final 4-way reduce for its w4 (redundant across hq,
    // but saves a barrier + LDS round-trip on the write critical path)
    float4 Cs = f4add(f4add(redc[0][w4], redc[1][w4]), f4add(redc[2][w4], redc[3][w4]));
    float4 Ds = f4add(f4add(redd[0][w4], redd[1][w4]), f4add(redd[2][w4], redd[3][w4]));
    nfloat4 f = { Cs.x / (Ds.x * (1.0f + 1e-8f)),
                  Cs.y / (Ds.y * (1.0f + 1e-8f)),
                  Cs.z / (Ds.z * (1.0f + 1e-8f)),
                  Cs.w / (Ds.w * (1.0f + 1e-8f)) };
    nfloat4* op = (nfloat4*)out + (size_t)(b * C + c) * H * W4;
    for (int i = t; i < H * W4; i += 256)
        __builtin_nontemporal_store(f, op + i);   // out never re-read
}

extern "C" void kernel_launch(void* const* d_in, const int* in_sizes, int n_in,
                              void* d_out, int out_size, void* d_ws, size_t ws_size,
                              hipStream_t stream) {
    const float* x = (const float*)d_in[0];
    float* out = (float*)d_out;
    float4* pcomp = (float4*)d_ws;                                // 32 MB
    float4* pden  = pcomp + (size_t)B * HC * C * W4;              // 512 KB

    k_pass1<<<B * HC, 512, 0, stream>>>(x, pcomp, pden);
    k_pass2<<<B * C,  256, 0, stream>>>(pcomp, pden, out);
}